// Round 1
// baseline (2528.627 us; speedup 1.0000x reference)
//
#include <hip/hip_runtime.h>
#include <hip/hip_bf16.h>

// JumpReLU SAE forward:
//   pre  = (x - b_dec) @ W_enc + b_enc          [8192, 16384]
//   feat = pre * (pre > threshold)
//   rec  = feat @ W_dec + b_dec                 [8192, 2048]
// out = [rec (8192*2048) | feat (8192*16384)] fp32
//
// Strategy: bf16 MFMA (16x16x32), m97-style 128x128 tile, BK=32,
// global_load_lds width-16 staging, both GEMMs in A[M,K] x Bt[N,K]^T form.

#define BM 128
#define BN 128
#define BK 32

typedef __bf16 bf16x8 __attribute__((ext_vector_type(8)));
typedef float  f32x4  __attribute__((ext_vector_type(4)));

__device__ __forceinline__ short f2bf(float f) {
    unsigned u = __float_as_uint(f);
    unsigned r = u + 0x7FFF + ((u >> 16) & 1);   // round-to-nearest-even
    return (short)(r >> 16);
}

__device__ __forceinline__ void gl_lds16(const void* g, void* l) {
    __builtin_amdgcn_global_load_lds(
        (const __attribute__((address_space(1))) unsigned int*)g,
        (__attribute__((address_space(3))) unsigned int*)l, 16, 0, 0);
}

// ---- prep: xb[m][k] = bf16(x[m][k] - b_dec[k]), d_model = 2048 ----
__global__ __launch_bounds__(256) void prep_x(const float* __restrict__ x,
                                              const float* __restrict__ b_dec,
                                              short* __restrict__ xb) {
    int idx = (blockIdx.x * 256 + threadIdx.x) * 4;
    float4 v = *(const float4*)(x + idx);
    int k = idx & 2047;
    float4 b = *(const float4*)(b_dec + k);
    short4 o;
    o.x = f2bf(v.x - b.x);
    o.y = f2bf(v.y - b.y);
    o.z = f2bf(v.z - b.z);
    o.w = f2bf(v.w - b.w);
    *(short4*)(xb + idx) = o;
}

// ---- transpose + fp32->bf16: in [R][C] fp32 -> out [C][R] bf16 ----
__global__ __launch_bounds__(256) void transpose_cvt(const float* __restrict__ in,
                                                     short* __restrict__ out,
                                                     int R, int C) {
    __shared__ float tile[32][33];
    int c0 = blockIdx.x * 32;
    int r0 = blockIdx.y * 32;
    int tx = threadIdx.x, ty = threadIdx.y;   // (32, 8)
    for (int i = 0; i < 32; i += 8)
        tile[ty + i][tx] = in[(size_t)(r0 + ty + i) * C + (c0 + tx)];
    __syncthreads();
    for (int i = 0; i < 32; i += 8)
        out[(size_t)(c0 + ty + i) * R + (r0 + tx)] = f2bf(tile[tx][ty + i]);
}

// ---- GEMM: C[M][N] = A[M][K] * Bt[N][K]^T (+bias, optional JumpReLU) ----
// A, Bt bf16-bits. Cf fp32 out; Cb optional bf16 copy; thr optional JumpReLU.
__global__ __launch_bounds__(256) void gemm_bt(
    const short* __restrict__ A, const short* __restrict__ Bt,
    const float* __restrict__ bias, const float* __restrict__ thr,
    float* __restrict__ Cf, short* __restrict__ Cb,
    int M, int N, int K) {
    __shared__ short As[BM * BK];   // [128][32]
    __shared__ short Bs[BN * BK];   // [128][32]

    const int tid  = threadIdx.x;
    const int lane = tid & 63;
    const int wave = tid >> 6;      // 0..3
    const int wm = wave >> 1, wn = wave & 1;
    const int bm = blockIdx.x, bn = blockIdx.y;

    const short* Abase = A  + (size_t)bm * 128 * K;
    const short* Bbase = Bt + (size_t)bn * 128 * K;

    const int srow = lane >> 2;          // 0..15 within issue
    const int skof = (lane & 3) * 8;     // k element offset within BK row chunk

    f32x4 acc[4][4];
#pragma unroll
    for (int mi = 0; mi < 4; mi++)
#pragma unroll
        for (int ni = 0; ni < 4; ni++)
            acc[mi][ni] = (f32x4){0.f, 0.f, 0.f, 0.f};

    const int mrow = lane & 15;
    const int kq   = (lane >> 4) * 8;

    for (int kt = 0; kt < K; kt += BK) {
        // stage A,B tiles: 8 wave-issues of 1KB each per tile; this wave does 2
#pragma unroll
        for (int i = 0; i < 2; i++) {
            int iid = wave + i * 4;              // 0..7
            int row = iid * 16 + srow;           // 0..127
            gl_lds16(Abase + (size_t)row * K + kt + skof, (char*)As + iid * 1024);
            gl_lds16(Bbase + (size_t)row * K + kt + skof, (char*)Bs + iid * 1024);
        }
        __syncthreads();

        bf16x8 af[4], bfr[4];
#pragma unroll
        for (int mi = 0; mi < 4; mi++)
            af[mi] = *(const bf16x8*)(As + (wm * 64 + mi * 16 + mrow) * BK + kq);
#pragma unroll
        for (int ni = 0; ni < 4; ni++)
            bfr[ni] = *(const bf16x8*)(Bs + (wn * 64 + ni * 16 + mrow) * BK + kq);
#pragma unroll
        for (int mi = 0; mi < 4; mi++)
#pragma unroll
            for (int ni = 0; ni < 4; ni++)
                acc[mi][ni] = __builtin_amdgcn_mfma_f32_16x16x32_bf16(
                    af[mi], bfr[ni], acc[mi][ni], 0, 0, 0);
        __syncthreads();
    }

    // epilogue: D[row=(lane>>4)*4+r][col=lane&15] per 16x16 tile
    const int colbase = bn * 128 + wn * 64;
    const int rowbase = bm * 128 + wm * 64;
#pragma unroll
    for (int mi = 0; mi < 4; mi++) {
        int row0 = rowbase + mi * 16 + (lane >> 4) * 4;
#pragma unroll
        for (int ni = 0; ni < 4; ni++) {
            int col = colbase + ni * 16 + mrow;
            float bz = bias[col];
            float tz = thr ? thr[col] : 0.f;
#pragma unroll
            for (int r = 0; r < 4; r++) {
                float v = acc[mi][ni][r] + bz;
                if (thr) v = (v > tz) ? v : 0.f;
                size_t off = (size_t)(row0 + r) * N + col;
                Cf[off] = v;
                if (Cb) Cb[off] = f2bf(v);
            }
        }
    }
}

extern "C" void kernel_launch(void* const* d_in, const int* in_sizes, int n_in,
                              void* d_out, int out_size, void* d_ws, size_t ws_size,
                              hipStream_t stream) {
    const float* x      = (const float*)d_in[0];   // [8192][2048]
    const float* W_enc  = (const float*)d_in[1];   // [2048][16384]
    const float* b_enc  = (const float*)d_in[2];   // [16384]
    const float* thr    = (const float*)d_in[3];   // [16384]
    const float* W_dec  = (const float*)d_in[4];   // [16384][2048]
    const float* b_dec  = (const float*)d_in[5];   // [2048]

    const int N = 8192, DM = 2048, DS = 16384;

    float* recon = (float*)d_out;                       // [8192][2048]
    float* feats = (float*)d_out + (size_t)N * DM;      // [8192][16384]

    char* ws = (char*)d_ws;
    short* xb    = (short*)ws;                            // 32MB  [8192][2048]
    short* wencT = (short*)(ws + ((size_t)32 << 20));     // 64MB  [16384][2048]
    short* wdecT = (short*)(ws + ((size_t)96 << 20));     // 64MB  [2048][16384]
    short* fb    = (short*)(ws + ((size_t)160 << 20));    // 256MB [8192][16384]

    prep_x<<<(N * DM) / (256 * 4), 256, 0, stream>>>(x, b_dec, xb);
    transpose_cvt<<<dim3(DS / 32, DM / 32), dim3(32, 8), 0, stream>>>(W_enc, wencT, DM, DS);
    transpose_cvt<<<dim3(DM / 32, DS / 32), dim3(32, 8), 0, stream>>>(W_dec, wdecT, DS, DM);

    // encode + JumpReLU: feats = JumpReLU((x-b_dec) @ W_enc + b_enc)
    gemm_bt<<<dim3(N / 128, DS / 128), 256, 0, stream>>>(
        xb, wencT, b_enc, thr, feats, fb, N, DS, DM);
    // decode: recon = feats @ W_dec + b_dec
    gemm_bt<<<dim3(N / 128, DM / 128), 256, 0, stream>>>(
        fb, wdecT, b_dec, nullptr, recon, nullptr, N, DM, DS);
}